// Round 3
// baseline (375.433 us; speedup 1.0000x reference)
//
#include <hip/hip_runtime.h>
#include <hip/hip_fp16.h>

// ---------------------------------------------------------------------------
// GCN forward: 2x GCNConv(relu) + global_mean_pool + linear
// R17: 7-dispatch pipeline; CSR build via global atomics (no LDS histograms),
// gemm staging conflict-free via pre-transposed fp16 W.
//   D0 k_prep    : zero deg; W1t/W2t = fp16(W^T)  (~3us)
//   D1 k_build   : edge scatter: slot=atomicAdd(deg[d]); esrc[d*CAP+slot]=s
//   D2 k_gemm128 : XW = fp16(rsqrt(deg+1) * (x@W1))   (pre-scaled rows)
//   D3 k_agg128  : H = relu(dn*(sum XW[s] + XW[d]) + b1), w in {0,1}
//   D4 k_gemm64  : XW2 = fp16(rsqrt(deg+1) * (H@W2))
//   D5 k_agg64   : fused head dot -> dnode[node] (contention-free)
//   D6 k_poolfinal: per-graph mean + lin_b (binary search, no atomics)
// R16 LESSONS: (a) gemm W-staging scalar b16 writes at word-stride 272 were a
// 16-way bank conflict (1.3e7 cycles) -> gemm was ~50us, not 12. Fixed via
// pre-transposed fp16 W + ds_write_b128 staging. (b) split/bucket LDS-atomic
// histograms (~16K atomics/block, random banks) serialized ~27us each ->
// replaced by device-scope atomicAdd on deg[] (spread over 400KB, L2/MALL).
// (c) EDGEW dis[src] gather cost agg128 +10us -> restored pre-scaled rows.
// R15 LESSON: mean-pool must stay contention-free (dnode + poolfinal).
// aggs at 8x-XCD-L2 compulsory gather floor (~190MB, ~60us each).
// ---------------------------------------------------------------------------

#define CAP 48  // esrc slots per node; deg ~ Poisson(16), P(max>=48) ~ 1e-7

typedef _Float16 half8 __attribute__((ext_vector_type(8)));
typedef _Float16 half4v __attribute__((ext_vector_type(4)));
typedef float f32x4 __attribute__((ext_vector_type(4)));

// zero deg; transpose W1[128][128], W2[128][64] to fp16 [c][128].
__global__ __launch_bounds__(256) void k_prep(const float* __restrict__ W1,
                                              const float* __restrict__ W2,
                                              _Float16* __restrict__ W1t,
                                              _Float16* __restrict__ W2t,
                                              int* __restrict__ deg, int N) {
  int T = gridDim.x * 256;
  int i0 = blockIdx.x * 256 + threadIdx.x;
  for (int i = i0; i < N; i += T) deg[i] = 0;
  for (int i = i0; i < 128 * 128; i += T)
    W1t[(i & 127) * 128 + (i >> 7)] = (_Float16)W1[i];
  for (int i = i0; i < 128 * 64; i += T)
    W2t[(i & 63) * 128 + (i >> 6)] = (_Float16)W2[i];
}

// edge-centric CSR build: device-scope atomic slot allocation + 4B scatter.
// No LDS. deg[d] ends as true in-degree (even past CAP; overflow edges drop).
__global__ __launch_bounds__(256) void k_build(const int* __restrict__ src,
                                               const int* __restrict__ dst,
                                               int* __restrict__ deg,
                                               int* __restrict__ esrc, int E) {
  int stride = gridDim.x * 256;
  for (int i = blockIdx.x * 256 + threadIdx.x; i < E; i += stride) {
    int s = src[i], d = dst[i];
    int slot = atomicAdd(&deg[d], 1);
    if (slot < CAP) esrc[(size_t)d * CAP + slot] = s;
  }
}

// out[nrows, COLS] (fp16) = [rsqrt(deg+1) *] (A[nrows, K] @ Wt^T).
// Wt_g is PRE-TRANSPOSED fp16 [COLS][K] -> staging is half8 loads +
// ds_write_b128 (conflict-free; R16's scalar-b16 transpose staging was a
// 16-way bank conflict). MFMA 16x16x32_f16, 64 rows x COLS per block.
// Layouts (m89/m120): A[m=lane&15][k=quad*8+j]; B[k][n=lane&15];
// D col=lane&15, row=quad*4+reg.
template <int COLS, int K, typename AT, bool SCALE>
__global__ __launch_bounds__(256) void k_gemm(const AT* __restrict__ A,
                                              const _Float16* __restrict__ Wt_g,
                                              const int* __restrict__ deg,
                                              __half* __restrict__ out,
                                              int nrows) {
  constexpr int KP = K + 8;  // padded LDS stride (halves)
  __shared__ _Float16 As[64 * KP];
  __shared__ _Float16 Wt[COLS * KP];
  int t = threadIdx.x;
  int row0 = blockIdx.x * 64;

  // stage W^T (already fp16 [COLS][K]): vector copy, conflict-free
  {
    constexpr int K8 = K / 8;
    for (int i = t; i < COLS * K8; i += 256) {
      int c = i / K8, k8 = (i % K8) * 8;
      *(half8*)&Wt[c * KP + k8] = *(const half8*)&Wt_g[c * K + k8];
    }
  }
  // stage A tile (fp16), zero-fill OOB rows
  if constexpr (sizeof(AT) == 4) {
    constexpr int F4 = K / 4;
    for (int id = t; id < 64 * F4; id += 256) {
      int r = id / F4, kq = (id % F4) * 4;
      int grow = row0 + r;
      float4 av = (grow < nrows) ? *(const float4*)&A[(size_t)grow * K + kq]
                                 : make_float4(0.f, 0.f, 0.f, 0.f);
      half4v hv = {(_Float16)av.x, (_Float16)av.y, (_Float16)av.z,
                   (_Float16)av.w};
      *(half4v*)&As[r * KP + kq] = hv;  // 8B write, conflict-free pattern
    }
  } else {
    constexpr int H8 = K / 8;
    for (int id = t; id < 64 * H8; id += 256) {
      int r = id / H8, kq = (id % H8) * 8;
      int grow = row0 + r;
      half8 av = (grow < nrows)
                     ? *(const half8*)&A[(size_t)grow * K + kq]
                     : (half8){0, 0, 0, 0, 0, 0, 0, 0};
      *(half8*)&As[r * KP + kq] = av;
    }
  }
  __syncthreads();

  int wave = t >> 6, lane = t & 63;
  int m = lane & 15;     // A row / B col / D col within 16-tile
  int quad = lane >> 4;  // k-group for A/B; row-group for D
  constexpr int NT = COLS / 16;

  f32x4 acc[NT];
#pragma unroll
  for (int ct = 0; ct < NT; ++ct) acc[ct] = (f32x4){0.f, 0.f, 0.f, 0.f};

  const _Float16* arow = &As[(wave * 16 + m) * KP + quad * 8];
#pragma unroll
  for (int ks = 0; ks < K; ks += 32) {
    half8 af = *(const half8*)&arow[ks];
#pragma unroll
    for (int ct = 0; ct < NT; ++ct) {
      half8 bf = *(const half8*)&Wt[(ct * 16 + m) * KP + quad * 8 + ks];
      acc[ct] = __builtin_amdgcn_mfma_f32_16x16x32_f16(af, bf, acc[ct], 0, 0, 0);
    }
  }

  // epilogue: dn-scale -> LDS transpose (reuse As; DP=COLS+4) -> coalesced
  // half8 row stores.
  __syncthreads();  // all As reads done
  _Float16* Ds = As;
  constexpr int DP = COLS + 4;
#pragma unroll
  for (int j = 0; j < 4; ++j) {
    int rl = wave * 16 + quad * 4 + j;
    int gr = row0 + rl;
    float dn = 1.f;
    if constexpr (SCALE)
      dn = (gr < nrows) ? rsqrtf((float)(deg[gr] + 1)) : 0.f;
#pragma unroll
    for (int ct = 0; ct < NT; ++ct)
      Ds[rl * DP + ct * 16 + m] = (_Float16)(acc[ct][j] * dn);
  }
  __syncthreads();
  constexpr int C8 = COLS / 8;
  for (int id = t; id < 64 * C8; id += 256) {
    int r = id / C8, c8 = (id % C8) * 8;
    int gr = row0 + r;
    if (gr < nrows)
      *(half8*)&out[(size_t)gr * COLS + c8] = *(const half8*)&Ds[r * DP + c8];
  }
}

// wave per node; COLS/8 lanes per edge-row (16B half8 loads), NG edge groups
// per wave, depth-2 pipeline. fp32 accumulate. H rows pre-scaled by
// rsqrt(deg[src]+1); validity weight {0,1}. Edge list: esrc[node*CAP ..
// node*CAP+min(deg,CAP)). dn = rsqrt(deg[node]+1).
// FUSE=false: write fp16 row. FUSE=true: write scalar
// dnode[node] = relu_row . lin_w (contention-free; R15's global-atomic pool
// serialized 150K RMWs on 8 lines, 60us -> 671us).
template <int COLS, bool FUSE>
__global__ __launch_bounds__(256) void k_agg(const __half* __restrict__ H,
                                             const int* __restrict__ esrc,
                                             const int* __restrict__ deg,
                                             const float* __restrict__ bias,
                                             __half* __restrict__ out,
                                             const float* __restrict__ lin_w,
                                             float* __restrict__ dnode, int n) {
  constexpr int LPE = COLS / 8;  // lanes per edge-row (16 or 8)
  constexpr int NG = 64 / LPE;   // edge groups per wave (4 or 8)
  int node = (blockIdx.x * 256 + threadIdx.x) >> 6;
  if (node >= n) return;
  int lane = threadIdx.x & 63;
  int group = lane / LPE;
  int c = (lane % LPE) * 8;

  float acc[8];
#pragma unroll
  for (int j = 0; j < 8; ++j) acc[j] = 0.f;

  int dg = deg[node];
  int b0 = node * CAP;
  int end = b0 + min(dg, CAP);
  int e0 = b0 + group;
  int e1 = e0 + NG;
  int s0 = 0, s1 = 0;
  float w0 = 0.f, w1 = 0.f;
  if (e0 < end) { s0 = esrc[e0]; w0 = 1.f; }
  if (e1 < end) { s1 = esrc[e1]; w1 = 1.f; }
  while (e0 < end) {
    float4 r0 = *(const float4*)&H[(size_t)s0 * COLS + c];
    float4 r1 = *(const float4*)&H[(size_t)s1 * COLS + c];
    int e2 = e0 + 2 * NG, e3 = e1 + 2 * NG;
    int s2 = 0, s3 = 0;
    float w2 = 0.f, w3 = 0.f;
    if (e2 < end) { s2 = esrc[e2]; w2 = 1.f; }
    if (e3 < end) { s3 = esrc[e3]; w3 = 1.f; }
    {
      union { float4 f4; __half2 h2[4]; } u;
      u.f4 = r0;
#pragma unroll
      for (int j = 0; j < 4; ++j) {
        float2 f = __half22float2(u.h2[j]);
        acc[2 * j + 0] = fmaf(f.x, w0, acc[2 * j + 0]);
        acc[2 * j + 1] = fmaf(f.y, w0, acc[2 * j + 1]);
      }
      u.f4 = r1;
#pragma unroll
      for (int j = 0; j < 4; ++j) {
        float2 f = __half22float2(u.h2[j]);
        acc[2 * j + 0] = fmaf(f.x, w1, acc[2 * j + 0]);
        acc[2 * j + 1] = fmaf(f.y, w1, acc[2 * j + 1]);
      }
    }
    e0 = e2; s0 = s2; w0 = w2;
    e1 = e3; s1 = s3; w1 = w3;
  }
#pragma unroll
  for (int m = LPE; m < 64; m <<= 1) {
#pragma unroll
    for (int j = 0; j < 8; ++j) acc[j] += __shfl_xor(acc[j], m, 64);
  }
  if (group == 0) {
    float dn = rsqrtf((float)(dg + 1));
    union { float4 f4; __half2 h2[4]; } u;
    u.f4 = *(const float4*)&H[(size_t)node * COLS + c];
    float o[8];
#pragma unroll
    for (int j = 0; j < 4; ++j) {
      float2 f = __half22float2(u.h2[j]);
      o[2 * j + 0] = fmaxf(fmaf(acc[2 * j + 0] + f.x, dn, bias[c + 2 * j + 0]), 0.f);
      o[2 * j + 1] = fmaxf(fmaf(acc[2 * j + 1] + f.y, dn, bias[c + 2 * j + 1]), 0.f);
    }
    if constexpr (FUSE) {
      float part = 0.f;
#pragma unroll
      for (int j = 0; j < 8; ++j) part = fmaf(o[j], lin_w[c + j], part);
      part += __shfl_xor(part, 1, 64);
      part += __shfl_xor(part, 2, 64);
      part += __shfl_xor(part, 4, 64);
      if (lane == 0) dnode[node] = part;
    } else {
      union { __half2 h2[4]; float4 f4; } ov;
#pragma unroll
      for (int j = 0; j < 4; ++j)
        ov.h2[j] = __floats2half2_rn(o[2 * j + 0], o[2 * j + 1]);
      *(float4*)&out[(size_t)node * COLS + c] = ov.f4;
    }
  }
}

__device__ inline int lower_bound_i(const int* a, int n, int v) {
  int lo = 0, hi = n;
  while (lo < hi) {
    int m = (lo + hi) >> 1;
    if (a[m] < v) lo = m + 1; else hi = m;
  }
  return lo;
}

// one block per graph: binary-search the sorted batch for this graph's node
// range, reduce dnode over it, emit out[g] = mean + lin_b. No atomics.
__global__ __launch_bounds__(256) void k_poolfinal(const float* __restrict__ dnode,
                                                   const int* __restrict__ batch,
                                                   const float* __restrict__ lin_b,
                                                   float* __restrict__ out, int N) {
  __shared__ int bounds[2];
  __shared__ float red[4];
  int g = blockIdx.x;
  int t = threadIdx.x;
  if (t == 0) bounds[0] = lower_bound_i(batch, N, g);
  if (t == 1) bounds[1] = lower_bound_i(batch, N, g + 1);
  __syncthreads();
  int lo = bounds[0], hi = bounds[1];
  float s = 0.f;
  for (int i = lo + t; i < hi; i += 256) s += dnode[i];
#pragma unroll
  for (int m = 1; m < 64; m <<= 1) s += __shfl_xor(s, m, 64);
  if ((t & 63) == 0) red[t >> 6] = s;
  __syncthreads();
  if (t == 0) {
    float sum = red[0] + red[1] + red[2] + red[3];
    float cnt = (float)(hi - lo);
    out[g] = sum / fmaxf(cnt, 1.f) + lin_b[0];
  }
}

extern "C" void kernel_launch(void* const* d_in, const int* in_sizes, int n_in,
                              void* d_out, int out_size, void* d_ws, size_t ws_size,
                              hipStream_t stream) {
  const float* x = (const float*)d_in[0];
  const int* edge = (const int*)d_in[1];
  const int* batch = (const int*)d_in[2];
  const float* W1 = (const float*)d_in[3];
  const float* b1 = (const float*)d_in[4];
  const float* W2 = (const float*)d_in[5];
  const float* b2 = (const float*)d_in[6];
  const float* lin_w = (const float*)d_in[7];
  const float* lin_b = (const float*)d_in[8];
  float* out = (float*)d_out;

  const int N = in_sizes[2];
  const int E = in_sizes[1] / 2;
  const int G = out_size;
  const int* esrc_in = edge;       // edge_index[0] = src
  const int* edst_in = edge + E;   // edge_index[1] = dst

  char* w = (char*)d_ws;
  size_t off = 0;
  auto take = [&](size_t bytes) {
    void* p = w + off;
    off += (bytes + 255) & ~(size_t)255;
    return p;
  };
  int* deg = (int*)take((size_t)N * 4);
  int* esrc = (int*)take((size_t)N * CAP * 4);      // 19.2 MB fixed-cap CSR
  __half* XW = (__half*)take((size_t)N * 128 * 2);  // fp16 XW / XW2
  __half* H = (__half*)take((size_t)N * 128 * 2);   // fp16 H1
  float* dnode = (float*)take((size_t)N * 4);       // per-node fused head dot
  _Float16* W1t = (_Float16*)take((size_t)128 * 128 * 2);
  _Float16* W2t = (_Float16*)take((size_t)64 * 128 * 2);
  (void)ws_size;
  (void)n_in;

  int GB = (N + 63) / 64;
  int ab = (int)(((size_t)N * 64 + 255) / 256);

  // D0: zero deg + fp16 W transposes
  k_prep<<<400, 256, 0, stream>>>(W1, W2, W1t, W2t, deg, N);
  // D1: CSR build via global atomics
  k_build<<<1024, 256, 0, stream>>>(esrc_in, edst_in, deg, esrc, E);
  // D2: XW = fp16(rsqrt(deg+1) * (x@W1))
  k_gemm<128, 128, float, true><<<GB, 256, 0, stream>>>(x, W1t, deg, XW, N);
  // D3: layer-1 agg -> H fp16
  k_agg<128, false><<<ab, 256, 0, stream>>>(XW, esrc, deg, b1, H, nullptr,
                                            nullptr, N);
  // D4: XW2 = fp16(rsqrt(deg+1) * (H@W2))
  k_gemm<64, 128, _Float16, true><<<GB, 256, 0, stream>>>(
      (const _Float16*)H, W2t, deg, XW, N);
  // D5: layer-2 agg + fused head -> dnode (contention-free)
  k_agg<64, true><<<ab, 256, 0, stream>>>(XW, esrc, deg, b2, nullptr, lin_w,
                                          dnode, N);
  // D6: per-graph mean + bias
  k_poolfinal<<<G, 256, 0, stream>>>(dnode, batch, lin_b, out, N);
}

// Round 4
// 278.535 us; speedup vs baseline: 1.3479x; 1.3479x over previous
//
#include <hip/hip_runtime.h>
#include <hip/hip_fp16.h>

// ---------------------------------------------------------------------------
// GCN forward: 2x GCNConv(relu) + global_mean_pool + linear
// R18: 7-dispatch pipeline = R14 structure + R17's conflict-free gemm.
//   D1 k_split   : deterministic multisplit (LDS hist, block-private slots)
//                  + 2 fat blocks transposing W1/W2 to fp16 [c][k]
//   D2 k_bucket  : per-bucket count/scan -> rr, dis, esrc
//   D3 k_gemm128 : XW = fp16(dis * (x@W1))      (pre-scaled rows)
//   D4 k_agg128  : H = relu(dn*(sum XW[s] + XW[d]) + b1), w in {0,1}
//   D5 k_gemm64  : XW2 = fp16(dis * (H@W2))
//   D6 k_agg64   : fused head dot -> dnode[node] (contention-free)
//   D7 k_poolfinal: per-graph mean + lin_b (binary search, no atomics)
// LESSONS LEDGER:
//  R15: global-atomic pool (150K RMWs on 8 lines) 60->671us. Contention-free
//       dnode+poolfinal only.
//  R16: gemm W-staging scalar-b16 at word-stride 272 = 16-way bank conflict
//       (1.3e7 cyc, ~30us over both gemms). Fixed: pre-transposed fp16 W +
//       vector LDS writes. Mixing gemm+split in one fat kernel tanked
//       occupancy (20%) -> don't mix heavy-LDS with light blocks.
//  R17: global-atomic slot alloc + dependent 4B random scatter (k_build) =
//       150us (4.4 atomics/cyc, 64B/edge write amplification). Two-level
//       LDS multisplit is ~4x faster -> reverted to R14 split/bucket.
// aggs at 8x-XCD-L2 compulsory gather floor (~190MB, ~60us each).
// ---------------------------------------------------------------------------

#define DN 512      // dst nodes per bucket
#define DSHIFT 9    // log2(DN)
#define SLOT 80     // slots per (split-block, bucket); mean 41.8, sigma 6.45

typedef _Float16 half8 __attribute__((ext_vector_type(8)));
typedef _Float16 half4v __attribute__((ext_vector_type(4)));
typedef float f32x4 __attribute__((ext_vector_type(4)));

// deterministic multisplit: block b histograms its 8192 edges, writes counts
// to hcnt[k*PB+b] (every entry written -> no zero-init), then scatters packed
// (src<<9 | local_dst) into its private SLOT-sized sub-region per bucket.
// Fat blocks b==PB / PB+1 transpose W1/W2 to fp16 [c][128] instead.
__global__ __launch_bounds__(1024) void k_split(
    const int* __restrict__ src, const int* __restrict__ dst,
    int* __restrict__ hcnt, int* __restrict__ binned, int E, int NBK, int PB,
    int CAPB, const float* __restrict__ W1, const float* __restrict__ W2,
    _Float16* __restrict__ W1t, _Float16* __restrict__ W2t) {
  __shared__ int h[256];
  int t = threadIdx.x;
  int b = blockIdx.x;
  if (b >= PB) {  // fat: weight transposes (independent of split work)
    if (b == PB) {
      for (int i = t; i < 128 * 128; i += 1024)
        W1t[(i & 127) * 128 + (i >> 7)] = (_Float16)W1[i];
    } else {
      for (int i = t; i < 128 * 64; i += 1024)
        W2t[(i & 63) * 128 + (i >> 6)] = (_Float16)W2[i];
    }
    return;
  }
  if (t < 256) h[t] = 0;
  __syncthreads();
  int base = b * 8192;
  int pk[8], bk[8];
  bool val[8];
#pragma unroll
  for (int j = 0; j < 8; ++j) {
    int i = base + j * 1024 + t;
    val[j] = (i < E);
    if (val[j]) {
      int s = src[i], d = dst[i];
      bk[j] = d >> DSHIFT;
      pk[j] = (s << DSHIFT) | (d & (DN - 1));
      atomicAdd(&h[bk[j]], 1);
    }
  }
  __syncthreads();
  for (int k = t; k < NBK; k += 1024) hcnt[k * PB + b] = min(h[k], SLOT);
  __syncthreads();
  if (t < 256) h[t] = 0;
  __syncthreads();
#pragma unroll
  for (int j = 0; j < 8; ++j) {
    if (val[j]) {
      int slot = atomicAdd(&h[bk[j]], 1);
      if (slot < SLOT) binned[bk[j] * CAPB + b * SLOT + slot] = pk[j];
    }
  }
}

// one block per bucket: LDS per-node count over valid slots + scan ->
// rr=(beg,end), dis; then LDS-cursor scatter of esrc into dense region.
__global__ __launch_bounds__(1024) void k_bucket(const int* __restrict__ binned,
                                                 const int* __restrict__ hcnt,
                                                 int2* __restrict__ rr,
                                                 float* __restrict__ dis,
                                                 int* __restrict__ esrc,
                                                 int N, int PB, int CAPB) {
  __shared__ int hc[1024];
  __shared__ int lcnt[DN];
  __shared__ int lscan[DN];
  int k = blockIdx.x;
  int t = threadIdx.x;
  int nbase = k << DSHIFT;
  for (int b2 = t; b2 < PB; b2 += 1024) hc[b2] = hcnt[k * PB + b2];
  if (t < DN) lcnt[t] = 0;
  __syncthreads();
  for (int idx = t; idx < CAPB; idx += 1024) {
    int b2 = idx / SLOT, j = idx - b2 * SLOT;
    if (j < hc[b2])
      atomicAdd(&lcnt[binned[k * CAPB + idx] & (DN - 1)], 1);
  }
  __syncthreads();
  if (t < DN) lscan[t] = lcnt[t];
  __syncthreads();
  for (int off = 1; off < DN; off <<= 1) {
    int v = (t < DN && t >= off) ? lscan[t - off] : 0;
    __syncthreads();
    if (t < DN) lscan[t] += v;
    __syncthreads();
  }
  int bstart = k * CAPB;
  if (t < DN) {
    int g = nbase + t;
    if (g < N) {
      int inc = lscan[t];
      int c = lcnt[t];
      rr[g] = make_int2(bstart + inc - c, bstart + inc);
      dis[g] = rsqrtf((float)(c + 1));
    }
    lcnt[t] = lscan[t] - lcnt[t];  // reuse as local exclusive cursor
  }
  __syncthreads();
  for (int idx = t; idx < CAPB; idx += 1024) {
    int b2 = idx / SLOT, j = idx - b2 * SLOT;
    if (j < hc[b2]) {
      int p = binned[k * CAPB + idx];
      int slot = atomicAdd(&lcnt[p & (DN - 1)], 1);
      esrc[bstart + slot] = (unsigned)p >> DSHIFT;
    }
  }
}

// out[nrows, COLS] (fp16) = [dis[row] *] (A[nrows, K] @ Wt^T).
// Wt_g is PRE-TRANSPOSED fp16 [COLS][K] -> staging is half8 loads +
// ds_write_b128 (conflict-free; R16's scalar-b16 transpose staging was a
// 16-way bank conflict). MFMA 16x16x32_f16, 64 rows x COLS per block.
// Layouts (m89/m120): A[m=lane&15][k=quad*8+j]; B[k][n=lane&15];
// D col=lane&15, row=quad*4+reg.
template <int COLS, int K, typename AT, bool SCALE>
__global__ __launch_bounds__(256) void k_gemm(const AT* __restrict__ A,
                                              const _Float16* __restrict__ Wt_g,
                                              const float* __restrict__ dis,
                                              __half* __restrict__ out,
                                              int nrows) {
  constexpr int KP = K + 8;  // padded LDS stride (halves)
  __shared__ _Float16 As[64 * KP];
  __shared__ _Float16 Wt[COLS * KP];
  int t = threadIdx.x;
  int row0 = blockIdx.x * 64;

  // stage W^T (already fp16 [COLS][K]): vector copy, conflict-free
  {
    constexpr int K8 = K / 8;
    for (int i = t; i < COLS * K8; i += 256) {
      int c = i / K8, k8 = (i % K8) * 8;
      *(half8*)&Wt[c * KP + k8] = *(const half8*)&Wt_g[c * K + k8];
    }
  }
  // stage A tile (fp16), zero-fill OOB rows
  if constexpr (sizeof(AT) == 4) {
    constexpr int F4 = K / 4;
    for (int id = t; id < 64 * F4; id += 256) {
      int r = id / F4, kq = (id % F4) * 4;
      int grow = row0 + r;
      float4 av = (grow < nrows) ? *(const float4*)&A[(size_t)grow * K + kq]
                                 : make_float4(0.f, 0.f, 0.f, 0.f);
      half4v hv = {(_Float16)av.x, (_Float16)av.y, (_Float16)av.z,
                   (_Float16)av.w};
      *(half4v*)&As[r * KP + kq] = hv;  // 8B write, conflict-free pattern
    }
  } else {
    constexpr int H8 = K / 8;
    for (int id = t; id < 64 * H8; id += 256) {
      int r = id / H8, kq = (id % H8) * 8;
      int grow = row0 + r;
      half8 av = (grow < nrows)
                     ? *(const half8*)&A[(size_t)grow * K + kq]
                     : (half8){0, 0, 0, 0, 0, 0, 0, 0};
      *(half8*)&As[r * KP + kq] = av;
    }
  }
  __syncthreads();

  int wave = t >> 6, lane = t & 63;
  int m = lane & 15;     // A row / B col / D col within 16-tile
  int quad = lane >> 4;  // k-group for A/B; row-group for D
  constexpr int NT = COLS / 16;

  f32x4 acc[NT];
#pragma unroll
  for (int ct = 0; ct < NT; ++ct) acc[ct] = (f32x4){0.f, 0.f, 0.f, 0.f};

  const _Float16* arow = &As[(wave * 16 + m) * KP + quad * 8];
#pragma unroll
  for (int ks = 0; ks < K; ks += 32) {
    half8 af = *(const half8*)&arow[ks];
#pragma unroll
    for (int ct = 0; ct < NT; ++ct) {
      half8 bf = *(const half8*)&Wt[(ct * 16 + m) * KP + quad * 8 + ks];
      acc[ct] = __builtin_amdgcn_mfma_f32_16x16x32_f16(af, bf, acc[ct], 0, 0, 0);
    }
  }

  // epilogue: dis-scale -> LDS transpose (reuse As; DP=COLS+4) -> coalesced
  // half8 row stores.
  __syncthreads();  // all As reads done
  _Float16* Ds = As;
  constexpr int DP = COLS + 4;
#pragma unroll
  for (int j = 0; j < 4; ++j) {
    int rl = wave * 16 + quad * 4 + j;
    int gr = row0 + rl;
    float dn = 1.f;
    if constexpr (SCALE) dn = (gr < nrows) ? dis[gr] : 0.f;
#pragma unroll
    for (int ct = 0; ct < NT; ++ct)
      Ds[rl * DP + ct * 16 + m] = (_Float16)(acc[ct][j] * dn);
  }
  __syncthreads();
  constexpr int C8 = COLS / 8;
  for (int id = t; id < 64 * C8; id += 256) {
    int r = id / C8, c8 = (id % C8) * 8;
    int gr = row0 + r;
    if (gr < nrows)
      *(half8*)&out[(size_t)gr * COLS + c8] = *(const half8*)&Ds[r * DP + c8];
  }
}

// wave per node; COLS/8 lanes per edge-row (16B half8 loads), NG edge groups
// per wave, depth-2 pipeline. H rows pre-scaled by dis[src]; validity weight
// {0,1}. fp32 accumulate. FUSE=false: write fp16 row. FUSE=true: write scalar
// dnode[node] = relu_row . lin_w (contention-free; R15 lesson: NO global
// atomics here).
template <int COLS, bool FUSE>
__global__ __launch_bounds__(256) void k_agg(const __half* __restrict__ H,
                                             const int2* __restrict__ rr,
                                             const int* __restrict__ esrc,
                                             const float* __restrict__ dis,
                                             const float* __restrict__ bias,
                                             __half* __restrict__ out,
                                             const float* __restrict__ lin_w,
                                             float* __restrict__ dnode, int n) {
  constexpr int LPE = COLS / 8;  // lanes per edge-row (16 or 8)
  constexpr int NG = 64 / LPE;   // edge groups per wave (4 or 8)
  int node = (blockIdx.x * 256 + threadIdx.x) >> 6;
  if (node >= n) return;
  int lane = threadIdx.x & 63;
  int group = lane / LPE;
  int c = (lane % LPE) * 8;

  float acc[8];
#pragma unroll
  for (int j = 0; j < 8; ++j) acc[j] = 0.f;

  int2 be = rr[node];
  int end = be.y;
  int e0 = be.x + group;
  int e1 = e0 + NG;
  int s0 = 0, s1 = 0;
  float w0 = 0.f, w1 = 0.f;
  if (e0 < end) { s0 = esrc[e0]; w0 = 1.f; }
  if (e1 < end) { s1 = esrc[e1]; w1 = 1.f; }
  while (e0 < end) {
    float4 r0 = *(const float4*)&H[(size_t)s0 * COLS + c];
    float4 r1 = *(const float4*)&H[(size_t)s1 * COLS + c];
    int e2 = e0 + 2 * NG, e3 = e1 + 2 * NG;
    int s2 = 0, s3 = 0;
    float w2 = 0.f, w3 = 0.f;
    if (e2 < end) { s2 = esrc[e2]; w2 = 1.f; }
    if (e3 < end) { s3 = esrc[e3]; w3 = 1.f; }
    {
      union { float4 f4; __half2 h2[4]; } u;
      u.f4 = r0;
#pragma unroll
      for (int j = 0; j < 4; ++j) {
        float2 f = __half22float2(u.h2[j]);
        acc[2 * j + 0] = fmaf(f.x, w0, acc[2 * j + 0]);
        acc[2 * j + 1] = fmaf(f.y, w0, acc[2 * j + 1]);
      }
      u.f4 = r1;
#pragma unroll
      for (int j = 0; j < 4; ++j) {
        float2 f = __half22float2(u.h2[j]);
        acc[2 * j + 0] = fmaf(f.x, w1, acc[2 * j + 0]);
        acc[2 * j + 1] = fmaf(f.y, w1, acc[2 * j + 1]);
      }
    }
    e0 = e2; s0 = s2; w0 = w2;
    e1 = e3; s1 = s3; w1 = w3;
  }
#pragma unroll
  for (int m = LPE; m < 64; m <<= 1) {
#pragma unroll
    for (int j = 0; j < 8; ++j) acc[j] += __shfl_xor(acc[j], m, 64);
  }
  if (group == 0) {
    float dn = dis[node];
    union { float4 f4; __half2 h2[4]; } u;
    u.f4 = *(const float4*)&H[(size_t)node * COLS + c];
    float o[8];
#pragma unroll
    for (int j = 0; j < 4; ++j) {
      float2 f = __half22float2(u.h2[j]);
      o[2 * j + 0] = fmaxf(fmaf(acc[2 * j + 0] + f.x, dn, bias[c + 2 * j + 0]), 0.f);
      o[2 * j + 1] = fmaxf(fmaf(acc[2 * j + 1] + f.y, dn, bias[c + 2 * j + 1]), 0.f);
    }
    if constexpr (FUSE) {
      float part = 0.f;
#pragma unroll
      for (int j = 0; j < 8; ++j) part = fmaf(o[j], lin_w[c + j], part);
      part += __shfl_xor(part, 1, 64);
      part += __shfl_xor(part, 2, 64);
      part += __shfl_xor(part, 4, 64);
      if (lane == 0) dnode[node] = part;
    } else {
      union { __half2 h2[4]; float4 f4; } ov;
#pragma unroll
      for (int j = 0; j < 4; ++j)
        ov.h2[j] = __floats2half2_rn(o[2 * j + 0], o[2 * j + 1]);
      *(float4*)&out[(size_t)node * COLS + c] = ov.f4;
    }
  }
}

__device__ inline int lower_bound_i(const int* a, int n, int v) {
  int lo = 0, hi = n;
  while (lo < hi) {
    int m = (lo + hi) >> 1;
    if (a[m] < v) lo = m + 1; else hi = m;
  }
  return lo;
}

// one block per graph: binary-search the sorted batch for this graph's node
// range, reduce dnode over it, emit out[g] = mean + lin_b. No atomics.
__global__ __launch_bounds__(256) void k_poolfinal(const float* __restrict__ dnode,
                                                   const int* __restrict__ batch,
                                                   const float* __restrict__ lin_b,
                                                   float* __restrict__ out, int N) {
  __shared__ int bounds[2];
  __shared__ float red[4];
  int g = blockIdx.x;
  int t = threadIdx.x;
  if (t == 0) bounds[0] = lower_bound_i(batch, N, g);
  if (t == 1) bounds[1] = lower_bound_i(batch, N, g + 1);
  __syncthreads();
  int lo = bounds[0], hi = bounds[1];
  float s = 0.f;
  for (int i = lo + t; i < hi; i += 256) s += dnode[i];
#pragma unroll
  for (int m = 1; m < 64; m <<= 1) s += __shfl_xor(s, m, 64);
  if ((t & 63) == 0) red[t >> 6] = s;
  __syncthreads();
  if (t == 0) {
    float sum = red[0] + red[1] + red[2] + red[3];
    float cnt = (float)(hi - lo);
    out[g] = sum / fmaxf(cnt, 1.f) + lin_b[0];
  }
}

extern "C" void kernel_launch(void* const* d_in, const int* in_sizes, int n_in,
                              void* d_out, int out_size, void* d_ws, size_t ws_size,
                              hipStream_t stream) {
  const float* x = (const float*)d_in[0];
  const int* edge = (const int*)d_in[1];
  const int* batch = (const int*)d_in[2];
  const float* W1 = (const float*)d_in[3];
  const float* b1 = (const float*)d_in[4];
  const float* W2 = (const float*)d_in[5];
  const float* b2 = (const float*)d_in[6];
  const float* lin_w = (const float*)d_in[7];
  const float* lin_b = (const float*)d_in[8];
  float* out = (float*)d_out;

  const int N = in_sizes[2];
  const int E = in_sizes[1] / 2;
  const int G = out_size;
  const int* esrc_in = edge;       // edge_index[0] = src
  const int* edst_in = edge + E;   // edge_index[1] = dst

  char* w = (char*)d_ws;
  size_t off = 0;
  auto take = [&](size_t bytes) {
    void* p = w + off;
    off += (bytes + 255) & ~(size_t)255;
    return p;
  };
  const int NBK = (N + DN - 1) / DN;   // 196 for N=100000 (must be <= 256)
  const int PB = (E + 8191) / 8192;    // 196 split blocks
  const int CAPB = PB * SLOT;          // 15680 slots per bucket region
  int* hcnt = (int*)take((size_t)NBK * PB * 4);
  int2* rr = (int2*)take((size_t)N * 8);
  float* dis = (float*)take((size_t)N * 4);
  int* esrc = (int*)take((size_t)NBK * CAPB * 4);   // bucketed, gap layout
  __half* XW = (__half*)take((size_t)N * 128 * 2);  // fp16 XW / XW2
  __half* H = (__half*)take((size_t)N * 128 * 2);   // fp16 H1; aliases binned
  float* dnode = (float*)take((size_t)N * 4);       // per-node fused head dot
  _Float16* W1t = (_Float16*)take((size_t)128 * 128 * 2);
  _Float16* W2t = (_Float16*)take((size_t)64 * 128 * 2);
  int* binned = (int*)H;  // NBK*CAPB*4 = 12.3MB <= N*256B; dead pre-agg128
  (void)ws_size;
  (void)n_in;

  int GB = (N + 63) / 64;
  int ab = (int)(((size_t)N * 64 + 255) / 256);

  // D1: multisplit + fat W transposes (blocks PB, PB+1)
  k_split<<<PB + 2, 1024, 0, stream>>>(esrc_in, edst_in, hcnt, binned, E, NBK,
                                       PB, CAPB, W1, W2, W1t, W2t);
  // D2: bucket CSR build -> rr, dis, esrc
  k_bucket<<<NBK, 1024, 0, stream>>>(binned, hcnt, rr, dis, esrc, N, PB, CAPB);
  // D3: XW = fp16(dis * (x@W1))
  k_gemm<128, 128, float, true><<<GB, 256, 0, stream>>>(x, W1t, dis, XW, N);
  // D4: layer-1 agg -> H fp16
  k_agg<128, false><<<ab, 256, 0, stream>>>(XW, rr, esrc, dis, b1, H, nullptr,
                                            nullptr, N);
  // D5: XW2 = fp16(dis * (H@W2))
  k_gemm<64, 128, _Float16, true><<<GB, 256, 0, stream>>>(
      (const _Float16*)H, W2t, dis, XW, N);
  // D6: layer-2 agg + fused head -> dnode (contention-free)
  k_agg<64, true><<<ab, 256, 0, stream>>>(XW, rr, esrc, dis, b2, nullptr,
                                          lin_w, dnode, N);
  // D7: per-graph mean + bias
  k_poolfinal<<<G, 256, 0, stream>>>(dnode, batch, lin_b, out, N);
}

// Round 5
// 269.596 us; speedup vs baseline: 1.3926x; 1.0332x over previous
//
#include <hip/hip_runtime.h>
#include <hip/hip_fp16.h>

// ---------------------------------------------------------------------------
// GCN forward: 2x GCNConv(relu) + global_mean_pool + linear
// R19: 6-dispatch pipeline = R18 + (a) XCD-aware bijective block swizzle in
// the agg kernels (esrc/rr slices become per-XCD L2-resident; kills the 8x
// replication of edge-list reads) + (b) gemm64 fused INTO agg128:
//   D1 k_split   : deterministic multisplit + 2 fat blocks: W1t/W2t fp16
//   D2 k_bucket  : per-bucket count/scan -> rr, dis, esrc
//   D3 k_gemm128 : XW = fp16(dis * (x@W1))      (pre-scaled rows)
//   D4 k_aggemm  : per 64-node tile: agg128 -> relu H-tile in LDS ->
//                  MFMA x W2 (reg-held frags) -> XW2 = fp16(dis*(H@W2))
//                  (H never touches global: -51MB traffic, -1 dispatch)
//   D5 k_agg64   : gather XW2, fused head dot -> dnode[node]
//   D6 k_poolfinal: per-graph mean + lin_b (binary search, no atomics)
// LESSONS LEDGER:
//  R15: global-atomic pool (150K RMWs on 8 lines) 60->671us. Contention-free
//       dnode+poolfinal only.
//  R16: gemm W-staging scalar-b16 at word-stride 272 = 16-way bank conflict
//       (1.3e7 cyc). Fixed: pre-transposed fp16 W + vector LDS writes.
//       Fat kernels: LDS/VGPR budget is per-kernel max over branches ->
//       never mix heavy-LDS blocks with occupancy-hungry blocks.
//  R17: global-atomic slot alloc + dependent 4B random scatter = 150us.
//       Two-level LDS multisplit ~4x faster.
//  R18: 278.5us. aggs 60us each @ 190MB FETCH (8x-XCD replication of XW
//       gather ~compulsory; esrc/rr replication is NOT -> swizzle).
// XW2 must NOT alias XW (k_aggemm reads XW while writing XW2).
// ---------------------------------------------------------------------------

#define DN 512      // dst nodes per bucket
#define DSHIFT 9    // log2(DN)
#define SLOT 80     // slots per (split-block, bucket); mean 41.8, sigma 6.45

typedef _Float16 half8 __attribute__((ext_vector_type(8)));
typedef _Float16 half4v __attribute__((ext_vector_type(4)));
typedef float f32x4 __attribute__((ext_vector_type(4)));

// bijective XCD swizzle (m204): hardware block h (round-robin h%8 -> XCD)
// gets logical work offset(h%8) + h/8, so each XCD covers a CONTIGUOUS
// logical range -> its rr/esrc slice stays L2-resident. Bijective for any n.
__device__ __forceinline__ int xcd_swz(int b, int n) {
  int x = b & 7, i = b >> 3;
  int q = n >> 3, r = n & 7;
  return x * q + min(x, r) + i;
}

// deterministic multisplit: block b histograms its 8192 edges, writes counts
// to hcnt[k*PB+b], then scatters packed (src<<9 | local_dst) into its private
// SLOT-sized sub-region per bucket. Fat blocks b==PB / PB+1 transpose W1/W2.
__global__ __launch_bounds__(1024) void k_split(
    const int* __restrict__ src, const int* __restrict__ dst,
    int* __restrict__ hcnt, int* __restrict__ binned, int E, int NBK, int PB,
    int CAPB, const float* __restrict__ W1, const float* __restrict__ W2,
    _Float16* __restrict__ W1t, _Float16* __restrict__ W2t) {
  __shared__ int h[256];
  int t = threadIdx.x;
  int b = blockIdx.x;
  if (b >= PB) {  // fat: weight transposes (independent of split work)
    if (b == PB) {
      for (int i = t; i < 128 * 128; i += 1024)
        W1t[(i & 127) * 128 + (i >> 7)] = (_Float16)W1[i];
    } else {
      for (int i = t; i < 128 * 64; i += 1024)
        W2t[(i & 63) * 128 + (i >> 6)] = (_Float16)W2[i];
    }
    return;
  }
  if (t < 256) h[t] = 0;
  __syncthreads();
  int base = b * 8192;
  int pk[8], bk[8];
  bool val[8];
#pragma unroll
  for (int j = 0; j < 8; ++j) {
    int i = base + j * 1024 + t;
    val[j] = (i < E);
    if (val[j]) {
      int s = src[i], d = dst[i];
      bk[j] = d >> DSHIFT;
      pk[j] = (s << DSHIFT) | (d & (DN - 1));
      atomicAdd(&h[bk[j]], 1);
    }
  }
  __syncthreads();
  for (int k = t; k < NBK; k += 1024) hcnt[k * PB + b] = min(h[k], SLOT);
  __syncthreads();
  if (t < 256) h[t] = 0;
  __syncthreads();
#pragma unroll
  for (int j = 0; j < 8; ++j) {
    if (val[j]) {
      int slot = atomicAdd(&h[bk[j]], 1);
      if (slot < SLOT) binned[bk[j] * CAPB + b * SLOT + slot] = pk[j];
    }
  }
}

// one block per bucket: LDS per-node count over valid slots + scan ->
// rr=(beg,end), dis; then LDS-cursor scatter of esrc into dense region.
__global__ __launch_bounds__(1024) void k_bucket(const int* __restrict__ binned,
                                                 const int* __restrict__ hcnt,
                                                 int2* __restrict__ rr,
                                                 float* __restrict__ dis,
                                                 int* __restrict__ esrc,
                                                 int N, int PB, int CAPB) {
  __shared__ int hc[1024];
  __shared__ int lcnt[DN];
  __shared__ int lscan[DN];
  int k = blockIdx.x;
  int t = threadIdx.x;
  int nbase = k << DSHIFT;
  for (int b2 = t; b2 < PB; b2 += 1024) hc[b2] = hcnt[k * PB + b2];
  if (t < DN) lcnt[t] = 0;
  __syncthreads();
  for (int idx = t; idx < CAPB; idx += 1024) {
    int b2 = idx / SLOT, j = idx - b2 * SLOT;
    if (j < hc[b2])
      atomicAdd(&lcnt[binned[k * CAPB + idx] & (DN - 1)], 1);
  }
  __syncthreads();
  if (t < DN) lscan[t] = lcnt[t];
  __syncthreads();
  for (int off = 1; off < DN; off <<= 1) {
    int v = (t < DN && t >= off) ? lscan[t - off] : 0;
    __syncthreads();
    if (t < DN) lscan[t] += v;
    __syncthreads();
  }
  int bstart = k * CAPB;
  if (t < DN) {
    int g = nbase + t;
    if (g < N) {
      int inc = lscan[t];
      int c = lcnt[t];
      rr[g] = make_int2(bstart + inc - c, bstart + inc);
      dis[g] = rsqrtf((float)(c + 1));
    }
    lcnt[t] = lscan[t] - lcnt[t];  // reuse as local exclusive cursor
  }
  __syncthreads();
  for (int idx = t; idx < CAPB; idx += 1024) {
    int b2 = idx / SLOT, j = idx - b2 * SLOT;
    if (j < hc[b2]) {
      int p = binned[k * CAPB + idx];
      int slot = atomicAdd(&lcnt[p & (DN - 1)], 1);
      esrc[bstart + slot] = (unsigned)p >> DSHIFT;
    }
  }
}

// out[nrows, COLS] (fp16) = [dis[row] *] (A[nrows, K] @ Wt^T).
// Wt_g is PRE-TRANSPOSED fp16 [COLS][K] -> staging is half8 loads +
// ds_write_b128 (conflict-free). MFMA 16x16x32_f16, 64 rows x COLS/block.
// Layouts (m89/m120): A[m=lane&15][k=quad*8+j]; B[k][n=lane&15];
// D col=lane&15, row=quad*4+reg.
template <int COLS, int K, typename AT, bool SCALE>
__global__ __launch_bounds__(256) void k_gemm(const AT* __restrict__ A,
                                              const _Float16* __restrict__ Wt_g,
                                              const float* __restrict__ dis,
                                              __half* __restrict__ out,
                                              int nrows) {
  constexpr int KP = K + 8;  // padded LDS stride (halves)
  __shared__ _Float16 As[64 * KP];
  __shared__ _Float16 Wt[COLS * KP];
  int t = threadIdx.x;
  int row0 = blockIdx.x * 64;

  // stage W^T (already fp16 [COLS][K]): vector copy, conflict-free
  {
    constexpr int K8 = K / 8;
    for (int i = t; i < COLS * K8; i += 256) {
      int c = i / K8, k8 = (i % K8) * 8;
      *(half8*)&Wt[c * KP + k8] = *(const half8*)&Wt_g[c * K + k8];
    }
  }
  // stage A tile (fp16), zero-fill OOB rows
  if constexpr (sizeof(AT) == 4) {
    constexpr int F4 = K / 4;
    for (int id = t; id < 64 * F4; id += 256) {
      int r = id / F4, kq = (id % F4) * 4;
      int grow = row0 + r;
      float4 av = (grow < nrows) ? *(const float4*)&A[(size_t)grow * K + kq]
                                 : make_float4(0.f, 0.f, 0.f, 0.f);
      half4v hv = {(_Float16)av.x, (_Float16)av.y, (_Float16)av.z,
                   (_Float16)av.w};
      *(half4v*)&As[r * KP + kq] = hv;  // 8B write, conflict-free pattern
    }
  } else {
    constexpr int H8 = K / 8;
    for (int id = t; id < 64 * H8; id += 256) {
      int r = id / H8, kq = (id % H8) * 8;
      int grow = row0 + r;
      half8 av = (grow < nrows)
                     ? *(const half8*)&A[(size_t)grow * K + kq]
                     : (half8){0, 0, 0, 0, 0, 0, 0, 0};
      *(half8*)&As[r * KP + kq] = av;
    }
  }
  __syncthreads();

  int wave = t >> 6, lane = t & 63;
  int m = lane & 15;     // A row / B col / D col within 16-tile
  int quad = lane >> 4;  // k-group for A/B; row-group for D
  constexpr int NT = COLS / 16;

  f32x4 acc[NT];
#pragma unroll
  for (int ct = 0; ct < NT; ++ct) acc[ct] = (f32x4){0.f, 0.f, 0.f, 0.f};

  const _Float16* arow = &As[(wave * 16 + m) * KP + quad * 8];
#pragma unroll
  for (int ks = 0; ks < K; ks += 32) {
    half8 af = *(const half8*)&arow[ks];
#pragma unroll
    for (int ct = 0; ct < NT; ++ct) {
      half8 bf = *(const half8*)&Wt[(ct * 16 + m) * KP + quad * 8 + ks];
      acc[ct] = __builtin_amdgcn_mfma_f32_16x16x32_f16(af, bf, acc[ct], 0, 0, 0);
    }
  }

  // epilogue: dis-scale -> LDS transpose (reuse As; DP=COLS+4) -> coalesced
  // half8 row stores.
  __syncthreads();  // all As reads done
  _Float16* Ds = As;
  constexpr int DP = COLS + 4;
#pragma unroll
  for (int j = 0; j < 4; ++j) {
    int rl = wave * 16 + quad * 4 + j;
    int gr = row0 + rl;
    float dn = 1.f;
    if constexpr (SCALE) dn = (gr < nrows) ? dis[gr] : 0.f;
#pragma unroll
    for (int ct = 0; ct < NT; ++ct)
      Ds[rl * DP + ct * 16 + m] = (_Float16)(acc[ct][j] * dn);
  }
  __syncthreads();
  constexpr int C8 = COLS / 8;
  for (int id = t; id < 64 * C8; id += 256) {
    int r = id / C8, c8 = (id % C8) * 8;
    int gr = row0 + r;
    if (gr < nrows)
      *(half8*)&out[(size_t)gr * COLS + c8] = *(const half8*)&Ds[r * DP + c8];
  }
}

// FUSED layer-1 agg + layer-2 gemm. Block = 64 nodes (matches MFMA tile).
// Phase A: each wave aggregates 16 nodes (same inner loop as k_agg<128>),
// group-0 lanes write the relu'd H row as half8 into LDS As[64][136]
// (16 lanes x contiguous 16B = conflict-free). Phase B: MFMA As @ W2
// (W2 frags reg-held from global fp16 W2t, L2-hot) -> XW2 = fp16(dis*(H@W2)).
// H never hits global memory (-51MB round-trip, -1 dispatch).
__global__ __launch_bounds__(256) void k_aggemm(
    const __half* __restrict__ XW, const int2* __restrict__ rr,
    const int* __restrict__ esrc, const float* __restrict__ dis,
    const float* __restrict__ bias, const _Float16* __restrict__ W2t,
    __half* __restrict__ XW2, int N) {
  constexpr int K = 128, KP = K + 8, COLS = 64, NT = COLS / 16;
  __shared__ _Float16 As[64 * KP];
  int t = threadIdx.x;
  int lane = t & 63, wave = t >> 6;
  int bid = xcd_swz((int)blockIdx.x, (int)gridDim.x);
  int row0 = bid * 64;

  int group = lane >> 4;    // 4 edge groups of 16 lanes
  int c = (lane & 15) * 8;  // column offset within 128

  for (int i = 0; i < 16; ++i) {
    int r = wave * 16 + i;
    int node = row0 + r;
    float acc[8];
#pragma unroll
    for (int j = 0; j < 8; ++j) acc[j] = 0.f;
    if (node < N) {
      int2 be = rr[node];
      int end = be.y;
      int e0 = be.x + group;
      int e1 = e0 + 4;
      int s0 = 0, s1 = 0;
      float w0 = 0.f, w1 = 0.f;
      if (e0 < end) { s0 = esrc[e0]; w0 = 1.f; }
      if (e1 < end) { s1 = esrc[e1]; w1 = 1.f; }
      while (e0 < end) {
        float4 r0 = *(const float4*)&XW[(size_t)s0 * 128 + c];
        float4 r1 = *(const float4*)&XW[(size_t)s1 * 128 + c];
        int e2 = e0 + 8, e3 = e1 + 8;
        int s2 = 0, s3 = 0;
        float w2 = 0.f, w3 = 0.f;
        if (e2 < end) { s2 = esrc[e2]; w2 = 1.f; }
        if (e3 < end) { s3 = esrc[e3]; w3 = 1.f; }
        {
          union { float4 f4; __half2 h2[4]; } u;
          u.f4 = r0;
#pragma unroll
          for (int j = 0; j < 4; ++j) {
            float2 f = __half22float2(u.h2[j]);
            acc[2 * j + 0] = fmaf(f.x, w0, acc[2 * j + 0]);
            acc[2 * j + 1] = fmaf(f.y, w0, acc[2 * j + 1]);
          }
          u.f4 = r1;
#pragma unroll
          for (int j = 0; j < 4; ++j) {
            float2 f = __half22float2(u.h2[j]);
            acc[2 * j + 0] = fmaf(f.x, w1, acc[2 * j + 0]);
            acc[2 * j + 1] = fmaf(f.y, w1, acc[2 * j + 1]);
          }
        }
        e0 = e2; s0 = s2; w0 = w2;
        e1 = e3; s1 = s3; w1 = w3;
      }
#pragma unroll
      for (int mm = 16; mm < 64; mm <<= 1) {
#pragma unroll
        for (int j = 0; j < 8; ++j) acc[j] += __shfl_xor(acc[j], mm, 64);
      }
    }
    if (group == 0) {
      half8 hv = (half8){0, 0, 0, 0, 0, 0, 0, 0};
      if (node < N) {
        float dn = dis[node];
        union { float4 f4; __half2 h2[4]; } u;
        u.f4 = *(const float4*)&XW[(size_t)node * 128 + c];
        _Float16* hp = (_Float16*)&hv;
#pragma unroll
        for (int j = 0; j < 4; ++j) {
          float2 f = __half22float2(u.h2[j]);
          hp[2 * j + 0] =
              (_Float16)fmaxf(fmaf(acc[2 * j + 0] + f.x, dn, bias[c + 2 * j + 0]), 0.f);
          hp[2 * j + 1] =
              (_Float16)fmaxf(fmaf(acc[2 * j + 1] + f.y, dn, bias[c + 2 * j + 1]), 0.f);
        }
      }
      *(half8*)&As[r * KP + c] = hv;  // 16 lanes x 16B contiguous: no conflict
    }
  }
  __syncthreads();

  // ---- phase B: XW2[row0..+64, 0..64) = dis * (As @ W2) ----
  int m = lane & 15, quad = lane >> 4;
  half8 bfr[4][NT];  // W2 fragments, reg-held (64 VGPR), global L2-hot
#pragma unroll
  for (int ks4 = 0; ks4 < 4; ++ks4)
#pragma unroll
    for (int ct = 0; ct < NT; ++ct)
      bfr[ks4][ct] =
          *(const half8*)&W2t[(ct * 16 + m) * K + ks4 * 32 + quad * 8];

  f32x4 acc2[NT];
#pragma unroll
  for (int ct = 0; ct < NT; ++ct) acc2[ct] = (f32x4){0.f, 0.f, 0.f, 0.f};
  const _Float16* arow = &As[(wave * 16 + m) * KP + quad * 8];
#pragma unroll
  for (int ks4 = 0; ks4 < 4; ++ks4) {
    half8 af = *(const half8*)&arow[ks4 * 32];
#pragma unroll
    for (int ct = 0; ct < NT; ++ct)
      acc2[ct] =
          __builtin_amdgcn_mfma_f32_16x16x32_f16(af, bfr[ks4][ct], acc2[ct], 0, 0, 0);
  }
  __syncthreads();  // all As reads done before reuse as Ds
  _Float16* Ds = As;
  constexpr int DP = COLS + 4;
#pragma unroll
  for (int j = 0; j < 4; ++j) {
    int rl = wave * 16 + quad * 4 + j;
    int gr = row0 + rl;
    float dn = (gr < N) ? dis[gr] : 0.f;
#pragma unroll
    for (int ct = 0; ct < NT; ++ct)
      Ds[rl * DP + ct * 16 + m] = (_Float16)(acc2[ct][j] * dn);
  }
  __syncthreads();
  for (int id = t; id < 64 * 8; id += 256) {
    int r = id / 8, c8 = (id % 8) * 8;
    int gr = row0 + r;
    if (gr < N)
      *(half8*)&XW2[(size_t)gr * COLS + c8] = *(const half8*)&Ds[r * DP + c8];
  }
}

// wave per node; COLS/8 lanes per edge-row (16B half8 loads), NG edge groups
// per wave, depth-2 pipeline. H rows pre-scaled by dis[src]; validity weight
// {0,1}. fp32 accumulate. XCD-swizzled block ids (esrc/rr L2 locality).
// FUSE=true: write scalar dnode[node] = relu_row . lin_w (contention-free;
// R15 lesson: NO global atomics here).
template <int COLS, bool FUSE>
__global__ __launch_bounds__(256) void k_agg(const __half* __restrict__ H,
                                             const int2* __restrict__ rr,
                                             const int* __restrict__ esrc,
                                             const float* __restrict__ dis,
                                             const float* __restrict__ bias,
                                             __half* __restrict__ out,
                                             const float* __restrict__ lin_w,
                                             float* __restrict__ dnode, int n) {
  constexpr int LPE = COLS / 8;  // lanes per edge-row (16 or 8)
  constexpr int NG = 64 / LPE;   // edge groups per wave (4 or 8)
  int bid = xcd_swz((int)blockIdx.x, (int)gridDim.x);
  int node = (bid * 256 + (int)threadIdx.x) >> 6;
  if (node >= n) return;
  int lane = threadIdx.x & 63;
  int group = lane / LPE;
  int c = (lane % LPE) * 8;

  float acc[8];
#pragma unroll
  for (int j = 0; j < 8; ++j) acc[j] = 0.f;

  int2 be = rr[node];
  int end = be.y;
  int e0 = be.x + group;
  int e1 = e0 + NG;
  int s0 = 0, s1 = 0;
  float w0 = 0.f, w1 = 0.f;
  if (e0 < end) { s0 = esrc[e0]; w0 = 1.f; }
  if (e1 < end) { s1 = esrc[e1]; w1 = 1.f; }
  while (e0 < end) {
    float4 r0 = *(const float4*)&H[(size_t)s0 * COLS + c];
    float4 r1 = *(const float4*)&H[(size_t)s1 * COLS + c];
    int e2 = e0 + 2 * NG, e3 = e1 + 2 * NG;
    int s2 = 0, s3 = 0;
    float w2 = 0.f, w3 = 0.f;
    if (e2 < end) { s2 = esrc[e2]; w2 = 1.f; }
    if (e3 < end) { s3 = esrc[e3]; w3 = 1.f; }
    {
      union { float4 f4; __half2 h2[4]; } u;
      u.f4 = r0;
#pragma unroll
      for (int j = 0; j < 4; ++j) {
        float2 f = __half22float2(u.h2[j]);
        acc[2 * j + 0] = fmaf(f.x, w0, acc[2 * j + 0]);
        acc[2 * j + 1] = fmaf(f.y, w0, acc[2 * j + 1]);
      }
      u.f4 = r1;
#pragma unroll
      for (int j = 0; j < 4; ++j) {
        float2 f = __half22float2(u.h2[j]);
        acc[2 * j + 0] = fmaf(f.x, w1, acc[2 * j + 0]);
        acc[2 * j + 1] = fmaf(f.y, w1, acc[2 * j + 1]);
      }
    }
    e0 = e2; s0 = s2; w0 = w2;
    e1 = e3; s1 = s3; w1 = w3;
  }
#pragma unroll
  for (int m = LPE; m < 64; m <<= 1) {
#pragma unroll
    for (int j = 0; j < 8; ++j) acc[j] += __shfl_xor(acc[j], m, 64);
  }
  if (group == 0) {
    float dn = dis[node];
    union { float4 f4; __half2 h2[4]; } u;
    u.f4 = *(const float4*)&H[(size_t)node * COLS + c];
    float o[8];
#pragma unroll
    for (int j = 0; j < 4; ++j) {
      float2 f = __half22float2(u.h2[j]);
      o[2 * j + 0] = fmaxf(fmaf(acc[2 * j + 0] + f.x, dn, bias[c + 2 * j + 0]), 0.f);
      o[2 * j + 1] = fmaxf(fmaf(acc[2 * j + 1] + f.y, dn, bias[c + 2 * j + 1]), 0.f);
    }
    if constexpr (FUSE) {
      float part = 0.f;
#pragma unroll
      for (int j = 0; j < 8; ++j) part = fmaf(o[j], lin_w[c + j], part);
      part += __shfl_xor(part, 1, 64);
      part += __shfl_xor(part, 2, 64);
      part += __shfl_xor(part, 4, 64);
      if (lane == 0) dnode[node] = part;
    } else {
      union { __half2 h2[4]; float4 f4; } ov;
#pragma unroll
      for (int j = 0; j < 4; ++j)
        ov.h2[j] = __floats2half2_rn(o[2 * j + 0], o[2 * j + 1]);
      *(float4*)&out[(size_t)node * COLS + c] = ov.f4;
    }
  }
}

__device__ inline int lower_bound_i(const int* a, int n, int v) {
  int lo = 0, hi = n;
  while (lo < hi) {
    int m = (lo + hi) >> 1;
    if (a[m] < v) lo = m + 1; else hi = m;
  }
  return lo;
}

// one block per graph: binary-search the sorted batch for this graph's node
// range, reduce dnode over it, emit out[g] = mean + lin_b. No atomics.
__global__ __launch_bounds__(256) void k_poolfinal(const float* __restrict__ dnode,
                                                   const int* __restrict__ batch,
                                                   const float* __restrict__ lin_b,
                                                   float* __restrict__ out, int N) {
  __shared__ int bounds[2];
  __shared__ float red[4];
  int g = blockIdx.x;
  int t = threadIdx.x;
  if (t == 0) bounds[0] = lower_bound_i(batch, N, g);
  if (t == 1) bounds[1] = lower_bound_i(batch, N, g + 1);
  __syncthreads();
  int lo = bounds[0], hi = bounds[1];
  float s = 0.f;
  for (int i = lo + t; i < hi; i += 256) s += dnode[i];
#pragma unroll
  for (int m = 1; m < 64; m <<= 1) s += __shfl_xor(s, m, 64);
  if ((t & 63) == 0) red[t >> 6] = s;
  __syncthreads();
  if (t == 0) {
    float sum = red[0] + red[1] + red[2] + red[3];
    float cnt = (float)(hi - lo);
    out[g] = sum / fmaxf(cnt, 1.f) + lin_b[0];
  }
}

extern "C" void kernel_launch(void* const* d_in, const int* in_sizes, int n_in,
                              void* d_out, int out_size, void* d_ws, size_t ws_size,
                              hipStream_t stream) {
  const float* x = (const float*)d_in[0];
  const int* edge = (const int*)d_in[1];
  const int* batch = (const int*)d_in[2];
  const float* W1 = (const float*)d_in[3];
  const float* b1 = (const float*)d_in[4];
  const float* W2 = (const float*)d_in[5];
  const float* b2 = (const float*)d_in[6];
  const float* lin_w = (const float*)d_in[7];
  const float* lin_b = (const float*)d_in[8];
  float* out = (float*)d_out;

  const int N = in_sizes[2];
  const int E = in_sizes[1] / 2;
  const int G = out_size;
  const int* esrc_in = edge;       // edge_index[0] = src
  const int* edst_in = edge + E;   // edge_index[1] = dst

  char* w = (char*)d_ws;
  size_t off = 0;
  auto take = [&](size_t bytes) {
    void* p = w + off;
    off += (bytes + 255) & ~(size_t)255;
    return p;
  };
  const int NBK = (N + DN - 1) / DN;   // 196 for N=100000 (must be <= 256)
  const int PB = (E + 8191) / 8192;    // 196 split blocks
  const int CAPB = PB * SLOT;          // 15680 slots per bucket region
  int* hcnt = (int*)take((size_t)NBK * PB * 4);
  int2* rr = (int2*)take((size_t)N * 8);
  float* dis = (float*)take((size_t)N * 4);
  int* esrc = (int*)take((size_t)NBK * CAPB * 4);     // bucketed, gap layout
  __half* XW = (__half*)take((size_t)N * 128 * 2);    // fp16 layer-1 XW
  __half* XW2 = (__half*)take((size_t)N * 64 * 2);    // fp16 layer-2 XW2
  float* dnode = (float*)take((size_t)N * 4);         // per-node head dot
  _Float16* W1t = (_Float16*)take((size_t)128 * 128 * 2);
  _Float16* W2t = (_Float16*)take((size_t)64 * 128 * 2);
  // binned aliases XW2: NBK*CAPB*4 = 12.29MB <= N*128B = 12.8MB; binned is
  // dead after k_bucket, XW2 first written in k_aggemm (D4).
  int* binned = (int*)XW2;
  (void)ws_size;
  (void)n_in;

  int GB = (N + 63) / 64;
  int ab = (int)(((size_t)N * 64 + 255) / 256);

  // D1: multisplit + fat W transposes (blocks PB, PB+1)
  k_split<<<PB + 2, 1024, 0, stream>>>(esrc_in, edst_in, hcnt, binned, E, NBK,
                                       PB, CAPB, W1, W2, W1t, W2t);
  // D2: bucket CSR build -> rr, dis, esrc
  k_bucket<<<NBK, 1024, 0, stream>>>(binned, hcnt, rr, dis, esrc, N, PB, CAPB);
  // D3: XW = fp16(dis * (x@W1))
  k_gemm<128, 128, float, true><<<GB, 256, 0, stream>>>(x, W1t, dis, XW, N);
  // D4: fused layer-1 agg + layer-2 gemm -> XW2 (H stays in LDS)
  k_aggemm<<<GB, 256, 0, stream>>>(XW, rr, esrc, dis, b1, W2t, XW2, N);
  // D5: layer-2 agg + fused head -> dnode (contention-free)
  k_agg<64, true><<<ab, 256, 0, stream>>>(XW2, rr, esrc, dis, b2, nullptr,
                                          lin_w, dnode, N);
  // D6: per-graph mean + bias
  k_poolfinal<<<G, 256, 0, stream>>>(dnode, batch, lin_b, out, N);
}